// Round 1
// baseline (857.871 us; speedup 1.0000x reference)
//
#include <hip/hip_runtime.h>
#include <stdint.h>

#define BB 16
#define NN 4096
#define CC 64
#define NPOINT 1024
#define KK 32
#define F1 64
#define F2 64
#define F3 128

#define FPS_T 512
#define PPT (NN / FPS_T)   // 8

typedef float v2f __attribute__((ext_vector_type(2)));

// ---------------- DPP 64-lane max-reduce helpers ----------------
#if defined(__has_builtin)
#if __has_builtin(__builtin_amdgcn_update_dpp)
#define HAS_DPP 1
#endif
#endif

#ifdef HAS_DPP
template <int CTRL>
__device__ __forceinline__ unsigned long long dpp_move64(unsigned long long k) {
    int lo = __builtin_amdgcn_update_dpp(0, (int)(unsigned)k,         CTRL, 0xF, 0xF, false);
    int hi = __builtin_amdgcn_update_dpp(0, (int)(unsigned)(k >> 32), CTRL, 0xF, 0xF, false);
    return ((unsigned long long)(unsigned)hi << 32) | (unsigned)lo;
}
__device__ __forceinline__ unsigned long long wave_max_key(unsigned long long key) {
    unsigned long long o;
    o = dpp_move64<0x111>(key); if (o > key) key = o;   // row_shr:1
    o = dpp_move64<0x112>(key); if (o > key) key = o;   // row_shr:2
    o = dpp_move64<0x114>(key); if (o > key) key = o;   // row_shr:4
    o = dpp_move64<0x118>(key); if (o > key) key = o;   // row_shr:8
    o = dpp_move64<0x142>(key); if (o > key) key = o;   // row_bcast15
    o = dpp_move64<0x143>(key); if (o > key) key = o;   // row_bcast31 -> lane63 has max
    return key;
}
#else
__device__ __forceinline__ unsigned long long wave_max_key(unsigned long long key) {
#pragma unroll
    for (int off = 32; off > 0; off >>= 1) {
        unsigned long long o = __shfl_xor(key, off, 64);
        if (o > key) key = o;
    }
    return key;
}
#endif

// shared-memory arena (union of FPS and MLP layouts)
// FPS : xs[4096] ys[4096] zs[4096] (49152) | wred 2x8 u64 (128) | cbuf 24 f (96)
// MLP : gbuf 32x68 (8704) | hbuf 32x64 (8192) | pmax 8x128 (4096) | cmask 64 u64 (512) | nbr 32 i (128)
// 56320 bytes: caps residency at 2 blocks/CU (was 3) -> less LDS-pipe/barrier
// contention with the latency-critical FPS blocks; MLP throughput has slack.
#define SMEM_BYTES 56320

__global__ __launch_bounds__(512)
void fused_kernel(const float* __restrict__ xyz,
                  const float* __restrict__ points,
                  const float* __restrict__ w0, const float* __restrict__ b0,
                  const float* __restrict__ w1, const float* __restrict__ b1,
                  const float* __restrict__ w2, const float* __restrict__ b2,
                  float* __restrict__ out_xyz,
                  float* __restrict__ out_points,
                  int* __restrict__ ctr) {
    __shared__ __align__(16) char smem[SMEM_BYTES];
    const int tid = threadIdx.x;

    if (blockIdx.x < BB) {
        // ================= FPS (blocks 0..15, resident first => no deadlock) ====
        asm volatile("s_setprio 3");   // out-issue co-resident MLP waves
        float* xs = (float*)smem;
        float* ys = xs + NN;
        float* zs = ys + NN;
        unsigned long long (*wred)[FPS_T / 64] =
            (unsigned long long (*)[FPS_T / 64])(smem + 49152);
        float* cbuf = (float*)(smem + 49280);   // 8 centroids staging (24 floats)

        const int b = blockIdx.x;
        const int lane = tid & 63, wid = tid >> 6;
        const float* __restrict__ xb = xyz + (size_t)b * (NN * 3);

        // packed pairs of points with PRE-NEGATED coords:
        // dx = cx + (-x) == -(x-cx) exactly; square identical to reference.
        v2f nx[4], ny[4], nz[4], d2[4];
#pragma unroll
        for (int j = 0; j < 4; ++j) {
            int p0 = tid + (2 * j) * FPS_T;
            int p1 = tid + (2 * j + 1) * FPS_T;
            float x0 = xb[p0 * 3 + 0], y0 = xb[p0 * 3 + 1], z0 = xb[p0 * 3 + 2];
            float x1 = xb[p1 * 3 + 0], y1 = xb[p1 * 3 + 1], z1 = xb[p1 * 3 + 2];
            xs[p0] = x0; ys[p0] = y0; zs[p0] = z0;
            xs[p1] = x1; ys[p1] = y1; zs[p1] = z1;
            nx[j].x = -x0; nx[j].y = -x1;
            ny[j].x = -y0; ny[j].y = -y1;
            nz[j].x = -z0; nz[j].y = -z1;
            d2[j].x = 1e10f; d2[j].y = 1e10f;
        }
        __syncthreads();

        float cx = xs[0], cy = ys[0], cz = zs[0];
        float* xo = out_xyz + (size_t)b * NPOINT * 3;

        for (int i = 0; i < NPOINT; ++i) {
            if (tid == 0) {             // stage centroid i (LDS only; cheap)
                cbuf[(i & 7) * 3 + 0] = cx;
                cbuf[(i & 7) * 3 + 1] = cy;
                cbuf[(i & 7) * 3 + 2] = cz;
            }
            float bd = -1.0f; int bp = 0;
            {
#pragma clang fp contract(off)
                // packed f32 (v_pk_add/v_pk_mul): exact mul/add rounding order
                // preserved vs reference; contraction disabled above.
                v2f cpx; cpx.x = cx; cpx.y = cx;
                v2f cpy; cpy.x = cy; cpy.y = cy;
                v2f cpz; cpz.x = cz; cpz.y = cz;
#pragma unroll
                for (int j = 0; j < 4; ++j) {
                    v2f dx = cpx + nx[j];
                    v2f dy = cpy + ny[j];
                    v2f dz = cpz + nz[j];
                    v2f xx = dx * dx;
                    v2f yy = dy * dy;
                    v2f zz = dz * dz;
                    v2f ss = xx + yy;
                    v2f dd = ss + zz;
                    v2f nd;
                    nd.x = fminf(d2[j].x, dd.x);
                    nd.y = fminf(d2[j].y, dd.y);
                    d2[j] = nd;
                    if (nd.x > bd) { bd = nd.x; bp = tid + (2 * j) * FPS_T; }
                    if (nd.y > bd) { bd = nd.y; bp = tid + (2 * j + 1) * FPS_T; }
                }
            }
            unsigned long long key = (((unsigned long long)__float_as_uint(bd)) << 32)
                                   | (unsigned int)(NN - 1 - bp);
            key = wave_max_key(key);
            if (lane == 63) wred[i & 1][wid] = key;
            __syncthreads();

            unsigned long long best = wred[i & 1][0];
#pragma unroll
            for (int w = 1; w < FPS_T / 64; ++w) {
                unsigned long long o = wred[i & 1][w];
                if (o > best) best = o;
            }
            int bi = (NN - 1) - (int)(best & 0xffffffffu);

            cx = xs[bi]; cy = ys[bi]; cz = zs[bi];

            // publish 8 centroids every 8 iters via RELAXED agent-scope (sc1,
            // LLC write-through) stores -- NO release fence, NO buffer_wbl2 on
            // the critical path. Pipelined: bump ctr for the PREVIOUS group
            // (its stores are certainly complete after vmcnt(0)), then issue
            // this group's stores without waiting.
            if (tid == 0 && (i & 7) == 7) {
                asm volatile("s_waitcnt vmcnt(0)" ::: "memory");
                if (i > 7)
                    __hip_atomic_store(&ctr[b * 16], i - 7,
                                       __ATOMIC_RELAXED, __HIP_MEMORY_SCOPE_AGENT);
                const unsigned* cbu = (const unsigned*)cbuf;
                unsigned* dst = (unsigned*)(xo + (size_t)(i - 7) * 3);
#pragma unroll
                for (int q = 0; q < 24; ++q)
                    __hip_atomic_store(dst + q, cbu[q],
                                       __ATOMIC_RELAXED, __HIP_MEMORY_SCOPE_AGENT);
            }
        }
        // final drain: make the last two groups visible
        if (tid == 0) {
            asm volatile("s_waitcnt vmcnt(0)" ::: "memory");
            __hip_atomic_store(&ctr[b * 16], NPOINT,
                               __ATOMIC_RELAXED, __HIP_MEMORY_SCOPE_AGENT);
        }
    } else {
        // ================= fused ball query + gather + MLP + maxpool ===========
        float (*gbuf)[68] = (float (*)[68])smem;                 // 32 x (67+pad)
        float (*hbuf)[F1] = (float (*)[F1])(smem + 8704);        // 32 x 64
        float (*pmax)[F3] = (float (*)[F3])(smem + 16896);       // 8 x 128
        unsigned long long* cmask = (unsigned long long*)(smem + 20992);
        int* nbr = (int*)(smem + 21504);

        const int gi = blockIdx.x - BB;
        const int s = gi >> 4;          // s-major: early blocks need early centroids
        const int b = gi & 15;
        const int g = b * NPOINT + s;
        const int f = tid & 63;
        const int wid = tid >> 6;       // 0..7

        // wait until centroid s is published (poison 0xAAAAAAAA < 0 => waits).
        // No ACQUIRE: producer data is sc1/LLC-coherent and our centroid reads
        // below are sc1 relaxed-atomic loads; __syncthreads orders the block.
        // (avoids 16384x buffer_inv L2 invalidations)
        if (tid == 0) {
            while (__hip_atomic_load(&ctr[b * 16], __ATOMIC_RELAXED,
                                     __HIP_MEMORY_SCOPE_AGENT) < s + 1)
                __builtin_amdgcn_s_sleep(2);
        }
        __syncthreads();

        // centroid via agent-scope loads (LLC-direct; immune to stale per-XCD L2)
        unsigned int ux = __hip_atomic_load((unsigned int*)&out_xyz[(size_t)g * 3 + 0],
                                            __ATOMIC_RELAXED, __HIP_MEMORY_SCOPE_AGENT);
        unsigned int uy = __hip_atomic_load((unsigned int*)&out_xyz[(size_t)g * 3 + 1],
                                            __ATOMIC_RELAXED, __HIP_MEMORY_SCOPE_AGENT);
        unsigned int uz = __hip_atomic_load((unsigned int*)&out_xyz[(size_t)g * 3 + 2],
                                            __ATOMIC_RELAXED, __HIP_MEMORY_SCOPE_AGENT);
        const float cx = __uint_as_float(ux);
        const float cy = __uint_as_float(uy);
        const float cz = __uint_as_float(uz);

        // ---- phase A1: 8 waves scan all 4096 points ----
        {
            const float* __restrict__ xb = xyz + (size_t)b * (NN * 3);
#pragma unroll
            for (int j = 0; j < 8; ++j) {
                int chunk = wid * 8 + j;
                int p = chunk * 64 + f;
                float x = xb[p * 3 + 0];
                float y = xb[p * 3 + 1];
                float z = xb[p * 3 + 2];
                float dx = __fsub_rn(cx, x);
                float dy = __fsub_rn(cy, y);
                float dz = __fsub_rn(cz, z);
                float d2 = __fadd_rn(__fadd_rn(__fmul_rn(dx, dx), __fmul_rn(dy, dy)),
                                     __fmul_rn(dz, dz));
                unsigned long long m = __ballot(d2 <= 0.04f);  // float32(0.2*0.2)
                if (f == 0) cmask[chunk] = m;
            }
        }
        __syncthreads();

        // ---- phase A2: wave 0 — ordered compaction of the 32 smallest indices ----
        if (tid < 64) {
            unsigned long long m = cmask[tid];
            int cnt = (int)__popcll(m);
            int v = cnt;
#pragma unroll
            for (int off = 1; off < 64; off <<= 1) {
                int u = __shfl_up(v, off, 64);
                if (tid >= off) v += u;
            }
            int excl = v - cnt;
            int total = __shfl(v, 63, 64);
            unsigned long long mm = m;
            int r = excl;
            while (mm && r < KK) {
                int bpos = __ffsll(mm) - 1;
                mm &= mm - 1;
                nbr[r++] = tid * 64 + bpos;
            }
            if (total < KK) {
                unsigned long long nz = __ballot(cnt > 0);
                int fchunk = __ffsll(nz) - 1;
                unsigned long long fm = cmask[fchunk];
                int first = fchunk * 64 + __ffsll(fm) - 1;
                if (tid >= total && tid < KK) nbr[tid] = first;
            }
        }
        __syncthreads();

        // ---- phase B: gather into LDS ----
        {
            const float* __restrict__ pb = points + (size_t)b * NN * CC;
#pragma unroll
            for (int m = 0; m < 4; ++m) {
                int k = wid + 8 * m;
                int idx = nbr[k] & (NN - 1);
                gbuf[k][f] = pb[(size_t)idx * CC + f];
            }
            if (tid < 96) {
                int k = tid & 31, q = tid >> 5;
                int idx = nbr[k] & (NN - 1);
                float v = xyz[((size_t)b * NN + idx) * 3 + q];
                float cq = (q == 0) ? cx : ((q == 1) ? cy : cz);
                gbuf[k][CC + q] = __fsub_rn(v, cq);
            }
        }
        __syncthreads();

        float acc[4];

        // ---- layer 1: 67 -> 64 ----
#pragma unroll
        for (int m = 0; m < 4; ++m) acc[m] = 0.0f;
#pragma unroll 4
        for (int c4 = 0; c4 < 64; c4 += 4) {
            float wv0 = w0[(c4 + 0) * F1 + f];
            float wv1 = w0[(c4 + 1) * F1 + f];
            float wv2 = w0[(c4 + 2) * F1 + f];
            float wv3 = w0[(c4 + 3) * F1 + f];
#pragma unroll
            for (int m = 0; m < 4; ++m) {
                float4 gv = *(const float4*)&gbuf[wid + 8 * m][c4];
                acc[m] = fmaf(gv.x, wv0, acc[m]);
                acc[m] = fmaf(gv.y, wv1, acc[m]);
                acc[m] = fmaf(gv.z, wv2, acc[m]);
                acc[m] = fmaf(gv.w, wv3, acc[m]);
            }
        }
        {
            float wv0 = w0[64 * F1 + f];
            float wv1 = w0[65 * F1 + f];
            float wv2 = w0[66 * F1 + f];
#pragma unroll
            for (int m = 0; m < 4; ++m) {
                int k = wid + 8 * m;
                acc[m] = fmaf(gbuf[k][64], wv0, acc[m]);
                acc[m] = fmaf(gbuf[k][65], wv1, acc[m]);
                acc[m] = fmaf(gbuf[k][66], wv2, acc[m]);
            }
        }
        {
            float bb = b0[f];
#pragma unroll
            for (int m = 0; m < 4; ++m)
                hbuf[wid + 8 * m][f] = fmaxf(acc[m] + bb, 0.0f);
        }
        __syncthreads();

        // ---- layer 2: 64 -> 64 ----
#pragma unroll
        for (int m = 0; m < 4; ++m) acc[m] = 0.0f;
#pragma unroll 4
        for (int c4 = 0; c4 < 64; c4 += 4) {
            float wv0 = w1[(c4 + 0) * F2 + f];
            float wv1 = w1[(c4 + 1) * F2 + f];
            float wv2 = w1[(c4 + 2) * F2 + f];
            float wv3 = w1[(c4 + 3) * F2 + f];
#pragma unroll
            for (int m = 0; m < 4; ++m) {
                float4 gv = *(const float4*)&hbuf[wid + 8 * m][c4];
                acc[m] = fmaf(gv.x, wv0, acc[m]);
                acc[m] = fmaf(gv.y, wv1, acc[m]);
                acc[m] = fmaf(gv.z, wv2, acc[m]);
                acc[m] = fmaf(gv.w, wv3, acc[m]);
            }
        }
        {
            float bb = b1[f];
#pragma unroll
            for (int m = 0; m < 4; ++m)
                gbuf[wid + 8 * m][f] = fmaxf(acc[m] + bb, 0.0f);
        }
        __syncthreads();

        // ---- layer 3: 64 -> 128 + maxpool ----
        float a0[4], a1[4];
#pragma unroll
        for (int m = 0; m < 4; ++m) { a0[m] = 0.0f; a1[m] = 0.0f; }
#pragma unroll 2
        for (int c4 = 0; c4 < 64; c4 += 4) {
            float w00 = w2[(c4 + 0) * F3 + f], w10 = w2[(c4 + 0) * F3 + f + 64];
            float w01 = w2[(c4 + 1) * F3 + f], w11 = w2[(c4 + 1) * F3 + f + 64];
            float w02 = w2[(c4 + 2) * F3 + f], w12 = w2[(c4 + 2) * F3 + f + 64];
            float w03 = w2[(c4 + 3) * F3 + f], w13 = w2[(c4 + 3) * F3 + f + 64];
#pragma unroll
            for (int m = 0; m < 4; ++m) {
                float4 gv = *(const float4*)&gbuf[wid + 8 * m][c4];
                a0[m] = fmaf(gv.x, w00, a0[m]);  a1[m] = fmaf(gv.x, w10, a1[m]);
                a0[m] = fmaf(gv.y, w01, a0[m]);  a1[m] = fmaf(gv.y, w11, a1[m]);
                a0[m] = fmaf(gv.z, w02, a0[m]);  a1[m] = fmaf(gv.z, w12, a1[m]);
                a0[m] = fmaf(gv.w, w03, a0[m]);  a1[m] = fmaf(gv.w, w13, a1[m]);
            }
        }
        {
            float pm0 = -1e30f, pm1 = -1e30f;
#pragma unroll
            for (int m = 0; m < 4; ++m) {
                pm0 = fmaxf(pm0, a0[m]);
                pm1 = fmaxf(pm1, a1[m]);
            }
            pmax[wid][f] = pm0;
            pmax[wid][f + 64] = pm1;
        }
        __syncthreads();
        if (tid < F3) {
            float v = pmax[0][tid];
#pragma unroll
            for (int w = 1; w < 8; ++w) v = fmaxf(v, pmax[w][tid]);
            v = fmaxf(v + b2[tid], 0.0f);   // relu(max+b) == max(relu(+b))
            out_points[(size_t)g * F3 + tid] = v;
        }
    }
}

extern "C" void kernel_launch(void* const* d_in, const int* in_sizes, int n_in,
                              void* d_out, int out_size, void* d_ws, size_t ws_size,
                              hipStream_t stream) {
    const float* xyz    = (const float*)d_in[0];
    const float* points = (const float*)d_in[1];
    const float* w0 = (const float*)d_in[2];
    const float* b0 = (const float*)d_in[3];
    const float* w1 = (const float*)d_in[4];
    const float* b1 = (const float*)d_in[5];
    const float* w2 = (const float*)d_in[6];
    const float* b2 = (const float*)d_in[7];

    float* out_xyz    = (float*)d_out;
    float* out_points = out_xyz + (size_t)BB * NPOINT * 3;
    int*   ctr        = (int*)d_ws;   // 16 counters, 64B stride (1 KiB used)

    fused_kernel<<<BB + BB * NPOINT, 512, 0, stream>>>(
        xyz, points, w0, b0, w1, b1, w2, b2, out_xyz, out_points, ctr);
}